// Round 6
// baseline (1231.624 us; speedup 1.0000x reference)
//
#include <hip/hip_runtime.h>
#include <hip/hip_bf16.h>

#define DIM 64
#define NREL 8
#define KS 512              // Sx width (k-permuted: k = ch*8 + r)
#define KTOT 576            // GEMM K: 512 + 64 root
#define BATCH 16

typedef __bf16 bf16x8 __attribute__((ext_vector_type(8)));
typedef float  f32x4  __attribute__((ext_vector_type(4)));

// ---------------- fused: hist (deg8 atomics) + initial gather xb ----------------
__global__ __launch_bounds__(256) void histgather_kernel(const int* __restrict__ dst,
                                                         const int* __restrict__ et,
                                                         int* __restrict__ deg8,
                                                         const int* __restrict__ x_idx,
                                                         const float* __restrict__ emb,
                                                         __bf16* __restrict__ xb,
                                                         int N, int E) {
    int i = blockIdx.x * 256 + threadIdx.x;
    if (i < N * DIM) {
        int n = i >> 6;
        int c = i & 63;
        xb[i] = (__bf16)emb[(size_t)x_idx[n] * DIM + c];
    }
    if (i < E) atomicAdd(&deg8[dst[i] * 8 + et[i]], 1);
}

// ---------------- scan1 + sum8 + invdeg fused ----------------
__global__ __launch_bounds__(256) void scan1_kernel(const int* __restrict__ deg8,
                                                    int* __restrict__ offs,
                                                    int* __restrict__ bsum,
                                                    float* __restrict__ invdeg, int N) {
    __shared__ int sd[256];
    int tid = threadIdx.x;
    int d = blockIdx.x * 256 + tid;
    int v = 0;
    if (d < N) {
#pragma unroll
        for (int r = 0; r < NREL; ++r) v += deg8[d * 8 + r];
        invdeg[d] = 1.0f / fmaxf((float)v, 1.0f);
    }
    sd[tid] = v;
    __syncthreads();
#pragma unroll
    for (int off = 1; off < 256; off <<= 1) {
        int t = (tid >= off) ? sd[tid - off] : 0;
        __syncthreads();
        sd[tid] += t;
        __syncthreads();
    }
    if (d < N) offs[d] = sd[tid] - v;
    if (tid == 255) bsum[blockIdx.x] = sd[255];
}

// ---------------- scan2 (block 0) + wcat (blocks >= 1) fused ----------------
// Wt[l][c][k]: k<512 -> k=ch*8+r maps to weight[l][r][ch][c]; k>=512 -> root[l][k-512][c]
__global__ __launch_bounds__(512) void scan2wcat_kernel(int* __restrict__ bsum, int nb,
                                                        const float* __restrict__ weight,
                                                        const float* __restrict__ root,
                                                        __bf16* __restrict__ Wt, int L) {
    if (blockIdx.x == 0) {
        __shared__ int sd[512];
        int tid = threadIdx.x;
        int v = (tid < nb) ? bsum[tid] : 0;
        sd[tid] = v;
        __syncthreads();
#pragma unroll
        for (int off = 1; off < 512; off <<= 1) {
            int t = (tid >= off) ? sd[tid - off] : 0;
            __syncthreads();
            sd[tid] += t;
            __syncthreads();
        }
        if (tid < nb) bsum[tid] = sd[tid] - v;
    } else {
        int idx = (blockIdx.x - 1) * 512 + threadIdx.x;
        int total = L * 64 * KTOT;
        if (idx >= total) return;
        int l = idx / (64 * KTOT);
        int rem = idx - l * 64 * KTOT;
        int c = rem / KTOT;
        int k = rem - c * KTOT;
        float w;
        if (k < KS) {
            int ch = k >> 3, r = k & 7;
            w = weight[(((l * 8 + r) * 64) + ch) * 64 + c];
        } else {
            w = root[(l * 64 + (k - KS)) * 64 + c];
        }
        Wt[idx] = (__bf16)w;
    }
}

// ---------------- scan3 + rpbuild + cursor zero fused ----------------
__global__ __launch_bounds__(256) void rpbuild_kernel(const int* __restrict__ deg8,
                                                      const int* __restrict__ offs,
                                                      const int* __restrict__ bsum,
                                                      int* __restrict__ rp,
                                                      int* __restrict__ cursor8,
                                                      int N, int E) {
    int d = blockIdx.x * 256 + threadIdx.x;
    if (d >= N) return;
    int base = offs[d] + bsum[blockIdx.x];
    int run = 0;
#pragma unroll
    for (int r = 0; r < NREL; ++r) {
        rp[d * 8 + r] = base + run;
        run += deg8[d * 8 + r];
        cursor8[d * 8 + r] = 0;
    }
    if (d == 0) rp[(size_t)N * 8] = E;
}

// ---------------- bucket: srcs sorted by (dst, rel) ----------------
__global__ __launch_bounds__(256) void bucket_kernel(const int* __restrict__ src,
                                                     const int* __restrict__ dst,
                                                     const int* __restrict__ et,
                                                     const int* __restrict__ rp,
                                                     int* __restrict__ cursor8,
                                                     int* __restrict__ srcs, int E) {
    int i = blockIdx.x * 256 + threadIdx.x;
    if (i >= E) return;
    int cell = dst[i] * 8 + et[i];
    int p = rp[cell] + atomicAdd(&cursor8[cell], 1);
    srcs[p] = src[i];
}

// ---------------- aggregate v3: wave/dst, batch-16 issue, LDS fp32 atomic accumulate
__global__ __launch_bounds__(256) void aggregate_kernel(const __bf16* __restrict__ xb,
                                                        const int* __restrict__ srcs,
                                                        const int* __restrict__ rp,
                                                        const float* __restrict__ invdeg,
                                                        __bf16* __restrict__ Sx, int N) {
    __shared__ float acc[4][NREL][64];    // 8 KB
    int wave = threadIdx.x >> 6;
    int lane = threadIdx.x & 63;
    int d0 = blockIdx.x * 4 + wave;
    if (d0 >= N) return;
    int d = __builtin_amdgcn_readfirstlane(d0);

    float* accw = &acc[wave][0][0];
#pragma unroll
    for (int r = 0; r < NREL; ++r) accw[r * 64 + lane] = 0.f;

    int rpv[9];
#pragma unroll
    for (int r = 0; r < 9; ++r) rpv[r] = rp[d * 8 + r];   // scalar loads
    int b0 = rpv[0], b8 = rpv[8];

    for (int j = b0; j < b8; j += BATCH) {
        float v[BATCH];
        int rr[BATCH];
#pragma unroll
        for (int b = 0; b < BATCH; ++b) {
            int jb = j + b;
            int jc = min(jb, b8 - 1);
            int s = srcs[jc];                               // scalar load (uniform)
            v[b] = (float)xb[(size_t)s * DIM + lane];       // independent gathers
            rr[b] = (jb >= rpv[1]) + (jb >= rpv[2]) + (jb >= rpv[3]) + (jb >= rpv[4])
                  + (jb >= rpv[5]) + (jb >= rpv[6]) + (jb >= rpv[7]);   // scalar
        }
#pragma unroll
        for (int b = 0; b < BATCH; ++b) {
            if (j + b < b8)                                 // uniform predicate
                atomicAdd(&accw[rr[b] * 64 + lane], v[b]);  // ds_add_f32, bank-clean
        }
    }

    float inv = invdeg[d];
    // k-permuted row: elem ch*8+r ; lane stores its 8 contiguous (ch=lane, r=0..7)
    float f[NREL];
#pragma unroll
    for (int r = 0; r < NREL; ++r) f[r] = accw[r * 64 + lane] * inv;
    __bf16 h[NREL];
#pragma unroll
    for (int r = 0; r < NREL; ++r) h[r] = (__bf16)f[r];
    *reinterpret_cast<bf16x8*>(Sx + (size_t)d * KS + lane * 8) = *reinterpret_cast<bf16x8*>(h);
}

// ---------------- GEMM: xout = relu([Sx | xb] @ Wcat + bias), B from global bf16 Wt
__global__ __launch_bounds__(256) void gemm_kernel(const __bf16* __restrict__ Sx,
                                                   const __bf16* __restrict__ xin,
                                                   const __bf16* __restrict__ Wt,    // [64][576]
                                                   const float* __restrict__ bias_l, // [64]
                                                   __bf16* __restrict__ xout, int N) {
    int wave = threadIdx.x >> 6;
    int lane = threadIdx.x & 63;
    int l15 = lane & 15;
    int lg  = lane >> 4;

    int n0 = blockIdx.x * 64;
    int row_a = n0 + 16 * wave + l15;
    if (row_a >= N) row_a = N - 1;
    const __bf16* arow = Sx  + (size_t)row_a * KS  + lg * 8;
    const __bf16* xrow = xin + (size_t)row_a * DIM + lg * 8;

    f32x4 acc[4];
#pragma unroll
    for (int t = 0; t < 4; ++t) acc[t] = (f32x4){0.f, 0.f, 0.f, 0.f};

#pragma unroll
    for (int kk = 0; kk < KTOT / 32; ++kk) {
        int k0 = kk * 32;
        bf16x8 av = (k0 < KS)
            ? *reinterpret_cast<const bf16x8*>(arow + k0)
            : *reinterpret_cast<const bf16x8*>(xrow + (k0 - KS));
#pragma unroll
        for (int t = 0; t < 4; ++t) {
            bf16x8 bv = *reinterpret_cast<const bf16x8*>(
                Wt + (size_t)(16 * t + l15) * KTOT + k0 + lg * 8);
            acc[t] = __builtin_amdgcn_mfma_f32_16x16x32_bf16(av, bv, acc[t], 0, 0, 0);
        }
    }

#pragma unroll
    for (int t = 0; t < 4; ++t) {
        int c = 16 * t + l15;
        float b = bias_l[c];
#pragma unroll
        for (int i = 0; i < 4; ++i) {
            int n = n0 + 16 * wave + 4 * lg + i;
            if (n < N) {
                float v = acc[t][i] + b;
                xout[(size_t)n * DIM + c] = (__bf16)fmaxf(v, 0.f);
            }
        }
    }
}

// ---------------- score ----------------
__global__ __launch_bounds__(256) void score_kernel(const __bf16* __restrict__ xb,
                                                    const int* __restrict__ s,
                                                    const int* __restrict__ t,
                                                    float* __restrict__ out, int T) {
    int i = blockIdx.x * 4 + (threadIdx.x >> 6);
    if (i >= T) return;
    int lane = threadIdx.x & 63;
    float p = (float)xb[(size_t)s[i] * DIM + lane] * (float)xb[(size_t)t[i] * DIM + lane];
#pragma unroll
    for (int off = 32; off > 0; off >>= 1) p += __shfl_down(p, off, 64);
    if (lane == 0) out[i] = p;
}

extern "C" void kernel_launch(void* const* d_in, const int* in_sizes, int n_in,
                              void* d_out, int out_size, void* d_ws, size_t ws_size,
                              hipStream_t stream) {
    const int*   x_idx  = (const int*)d_in[0];
    const int*   eidx   = (const int*)d_in[1];   // [2,E]
    const int*   etyp   = (const int*)d_in[2];   // [E]
    const int*   tidx   = (const int*)d_in[3];   // [2,T]
    const float* emb    = (const float*)d_in[4]; // [N,64]
    const float* weight = (const float*)d_in[5]; // [L,8,64,64]
    const float* root   = (const float*)d_in[6]; // [L,64,64]
    const float* bias   = (const float*)d_in[7]; // [L,64]

    int N = in_sizes[0];
    int E = in_sizes[2];
    int T = in_sizes[3] / 2;
    int L = in_sizes[5] / (NREL * DIM * DIM);

    const int* src = eidx;
    const int* dst = eidx + E;
    const int* ts  = tidx;
    const int* tt  = tidx + T;
    float* out = (float*)d_out;

    // ---- workspace carve-up ----
    char* p = (char*)d_ws;
    auto alloc = [&](size_t bytes) -> void* {
        void* r = (void*)p;
        p += (bytes + 255) & ~(size_t)255;
        return r;
    };
    __bf16* Sx      = (__bf16*)alloc((size_t)N * KS * sizeof(__bf16));
    __bf16* xb      = (__bf16*)alloc((size_t)N * DIM * sizeof(__bf16));
    __bf16* Wt      = (__bf16*)alloc((size_t)L * 64 * KTOT * sizeof(__bf16));
    int*    srcs    = (int*)   alloc(((size_t)E + 64) * sizeof(int));
    int*    deg8    = (int*)   alloc((size_t)N * 8 * 2 * sizeof(int));  // deg8 + cursor8 adjacent
    int*    cursor8 = deg8 + (size_t)N * 8;
    int*    rp      = (int*)   alloc(((size_t)N * 8 + 1) * sizeof(int));
    int*    offs    = (int*)   alloc((size_t)N * sizeof(int));
    float*  invdeg  = (float*) alloc((size_t)N * sizeof(float));
    int*    bsum    = (int*)   alloc(1024 * sizeof(int));

    int nb = (N + 255) / 256;

    // one memset zeroes deg8+cursor8 together
    hipMemsetAsync(deg8, 0, (size_t)N * 8 * 2 * sizeof(int), stream);
    histgather_kernel<<<((size_t)N * DIM + 255) / 256, 256, 0, stream>>>(
        dst, etyp, deg8, x_idx, emb, xb, N, E);
    scan1_kernel<<<nb, 256, 0, stream>>>(deg8, offs, bsum, invdeg, N);
    {
        int wtotal = L * 64 * KTOT;
        int wblocks = 1 + (wtotal + 511) / 512;
        scan2wcat_kernel<<<wblocks, 512, 0, stream>>>(bsum, nb, weight, root, Wt, L);
    }
    rpbuild_kernel<<<nb, 256, 0, stream>>>(deg8, offs, bsum, rp, cursor8, N, E);
    bucket_kernel<<<(E + 255) / 256, 256, 0, stream>>>(src, dst, etyp, rp, cursor8, srcs, E);

    int ntiles = (N + 63) / 64;
    for (int l = 0; l < L; ++l) {
        aggregate_kernel<<<(N + 3) / 4, 256, 0, stream>>>(xb, srcs, rp, invdeg, Sx, N);
        gemm_kernel<<<ntiles, 256, 0, stream>>>(Sx, xb,
                                                Wt + (size_t)l * 64 * KTOT,
                                                bias + (size_t)l * DIM,
                                                xb, N);
    }

    score_kernel<<<(T + 3) / 4, 256, 0, stream>>>(xb, ts, tt, out, T);
}

// Round 7
// 499.320 us; speedup vs baseline: 2.4666x; 2.4666x over previous
//
#include <hip/hip_runtime.h>
#include <hip/hip_bf16.h>

#define DIM 64
#define NREL 8
#define KS 512              // Sx width (k-permuted: k = ch*8 + r)
#define KTOT 576            // GEMM K: 512 + 64 root

typedef __bf16 bf16x8 __attribute__((ext_vector_type(8)));
typedef float  f32x4  __attribute__((ext_vector_type(4)));

// ---------------- fused: hist + initial gather xb + srcs sentinel prefill + zero row
__global__ __launch_bounds__(256) void histgather_kernel(const int* __restrict__ dst,
                                                         const int* __restrict__ et,
                                                         int* __restrict__ deg8,
                                                         const int* __restrict__ x_idx,
                                                         const float* __restrict__ emb,
                                                         __bf16* __restrict__ xb,
                                                         int* __restrict__ srcs,
                                                         int N, int E, int epad_cap) {
    int i = blockIdx.x * 256 + threadIdx.x;
    if (i < N * DIM) {
        int n = i >> 6;
        int c = i & 63;
        xb[i] = (__bf16)emb[(size_t)x_idx[n] * DIM + c];
    }
    if (i < DIM) xb[(size_t)N * DIM + i] = (__bf16)0.f;   // sentinel zero row
    if (i < epad_cap) srcs[i] = N;                        // padding -> sentinel
    if (i < E) atomicAdd(&deg8[dst[i] * 8 + et[i]], 1);
}

// ---------------- scan1 over per-dst PADDED totals + invdeg (true deg) ----------------
__global__ __launch_bounds__(256) void scan1_kernel(const int* __restrict__ deg8,
                                                    int* __restrict__ offs,
                                                    int* __restrict__ bsum,
                                                    float* __restrict__ invdeg, int N) {
    __shared__ int sd[256];
    int tid = threadIdx.x;
    int d = blockIdx.x * 256 + tid;
    int vpad = 0;
    if (d < N) {
        int vtrue = 0;
#pragma unroll
        for (int r = 0; r < NREL; ++r) {
            int dv = deg8[d * 8 + r];
            vtrue += dv;
            vpad += (dv + 3) & ~3;
        }
        invdeg[d] = 1.0f / fmaxf((float)vtrue, 1.0f);
    }
    sd[tid] = vpad;
    __syncthreads();
#pragma unroll
    for (int off = 1; off < 256; off <<= 1) {
        int t = (tid >= off) ? sd[tid - off] : 0;
        __syncthreads();
        sd[tid] += t;
        __syncthreads();
    }
    if (d < N) offs[d] = sd[tid] - vpad;
    if (tid == 255) bsum[blockIdx.x] = sd[255];
}

// ---------------- scan2 (block 0) + wcat (blocks >= 1) fused ----------------
// Wt[l][c][k]: k<512 -> k=ch*8+r maps weight[l][r][ch][c]; k>=512 -> root[l][k-512][c]
__global__ __launch_bounds__(512) void scan2wcat_kernel(int* __restrict__ bsum, int nb,
                                                        const float* __restrict__ weight,
                                                        const float* __restrict__ root,
                                                        __bf16* __restrict__ Wt, int L) {
    if (blockIdx.x == 0) {
        __shared__ int sd[512];
        int tid = threadIdx.x;
        int v = (tid < nb) ? bsum[tid] : 0;
        sd[tid] = v;
        __syncthreads();
#pragma unroll
        for (int off = 1; off < 512; off <<= 1) {
            int t = (tid >= off) ? sd[tid - off] : 0;
            __syncthreads();
            sd[tid] += t;
            __syncthreads();
        }
        if (tid < nb) bsum[tid] = sd[tid] - v;
    } else {
        int idx = (blockIdx.x - 1) * 512 + threadIdx.x;
        int total = L * 64 * KTOT;
        if (idx >= total) return;
        int l = idx / (64 * KTOT);
        int rem = idx - l * 64 * KTOT;
        int c = rem / KTOT;
        int k = rem - c * KTOT;
        float w;
        if (k < KS) {
            int ch = k >> 3, r = k & 7;
            w = weight[(((l * 8 + r) * 64) + ch) * 64 + c];
        } else {
            w = root[(l * 64 + (k - KS)) * 64 + c];
        }
        Wt[idx] = (__bf16)w;
    }
}

// ---------------- rp_pad build (padded per-cell starts) + cursor zero ----------------
__global__ __launch_bounds__(256) void rpbuild_kernel(const int* __restrict__ deg8,
                                                      const int* __restrict__ offs,
                                                      const int* __restrict__ bsum,
                                                      int* __restrict__ rp,
                                                      int* __restrict__ cursor8,
                                                      int N) {
    int d = blockIdx.x * 256 + threadIdx.x;
    if (d >= N) return;
    int base = offs[d] + bsum[blockIdx.x];
    int run = 0;
#pragma unroll
    for (int r = 0; r < NREL; ++r) {
        rp[d * 8 + r] = base + run;
        run += (deg8[d * 8 + r] + 3) & ~3;
        cursor8[d * 8 + r] = 0;
    }
    if (d == N - 1) rp[(size_t)N * 8] = base + run;   // E_pad total
}

// ---------------- bucket: srcs sorted by (dst, rel), padded cells ----------------
__global__ __launch_bounds__(256) void bucket_kernel(const int* __restrict__ src,
                                                     const int* __restrict__ dst,
                                                     const int* __restrict__ et,
                                                     const int* __restrict__ rp,
                                                     int* __restrict__ cursor8,
                                                     int* __restrict__ srcs, int E) {
    int i = blockIdx.x * 256 + threadIdx.x;
    if (i >= E) return;
    int cell = dst[i] * 8 + et[i];
    int p = rp[cell] + atomicAdd(&cursor8[cell], 1);
    srcs[p] = src[i];
}

// ---------------- aggregate v4: wave/dst; per-cell quads; scalar dwordx4 src loads
__global__ __launch_bounds__(256) void aggregate_kernel(const __bf16* __restrict__ xb,
                                                        const int* __restrict__ srcs,
                                                        const int* __restrict__ rp,
                                                        const float* __restrict__ invdeg,
                                                        __bf16* __restrict__ Sx, int N) {
    int d0 = blockIdx.x * 4 + (threadIdx.x >> 6);
    if (d0 >= N) return;
    int d = __builtin_amdgcn_readfirstlane(d0);
    int lane = threadIdx.x & 63;

    int rpv[9];
#pragma unroll
    for (int r = 0; r < 9; ++r) rpv[r] = rp[d * 8 + r];   // scalar loads (uniform)

    float facc[NREL];
#pragma unroll
    for (int r = 0; r < NREL; ++r) {                      // r compile-time -> named acc regs
        float acc = 0.f;
        for (int q = rpv[r]; q < rpv[r + 1]; q += 4) {    // uniform bounds, step 4
            int4 sv = *reinterpret_cast<const int4*>(srcs + q);   // s_load_dwordx4
            float v0 = (float)xb[(size_t)sv.x * DIM + lane];      // 4 independent gathers
            float v1 = (float)xb[(size_t)sv.y * DIM + lane];      // (sentinel N -> zero row)
            float v2 = (float)xb[(size_t)sv.z * DIM + lane];
            float v3 = (float)xb[(size_t)sv.w * DIM + lane];
            acc += (v0 + v1) + (v2 + v3);
        }
        facc[r] = acc;
    }

    float inv = invdeg[d];
    bf16x8 h;
#pragma unroll
    for (int r = 0; r < NREL; ++r) h[r] = (__bf16)(facc[r] * inv);
    // k-permuted row: element k = ch*8 + r, lane stores ch=lane -> 16B contiguous
    *reinterpret_cast<bf16x8*>(Sx + (size_t)d * KS + lane * 8) = h;
}

// ---------------- GEMM: xout = relu([Sx | xb] @ Wcat + bias), B from global bf16 Wt
__global__ __launch_bounds__(256) void gemm_kernel(const __bf16* __restrict__ Sx,
                                                   const __bf16* __restrict__ xin,
                                                   const __bf16* __restrict__ Wt,    // [64][576]
                                                   const float* __restrict__ bias_l, // [64]
                                                   __bf16* __restrict__ xout, int N) {
    int wave = threadIdx.x >> 6;
    int lane = threadIdx.x & 63;
    int l15 = lane & 15;
    int lg  = lane >> 4;

    int n0 = blockIdx.x * 64;
    int row_a = n0 + 16 * wave + l15;
    if (row_a >= N) row_a = N - 1;
    const __bf16* arow = Sx  + (size_t)row_a * KS  + lg * 8;
    const __bf16* xrow = xin + (size_t)row_a * DIM + lg * 8;

    f32x4 acc[4];
#pragma unroll
    for (int t = 0; t < 4; ++t) acc[t] = (f32x4){0.f, 0.f, 0.f, 0.f};

#pragma unroll
    for (int kk = 0; kk < KTOT / 32; ++kk) {
        int k0 = kk * 32;
        bf16x8 av = (k0 < KS)
            ? *reinterpret_cast<const bf16x8*>(arow + k0)
            : *reinterpret_cast<const bf16x8*>(xrow + (k0 - KS));
#pragma unroll
        for (int t = 0; t < 4; ++t) {
            bf16x8 bv = *reinterpret_cast<const bf16x8*>(
                Wt + (size_t)(16 * t + l15) * KTOT + k0 + lg * 8);
            acc[t] = __builtin_amdgcn_mfma_f32_16x16x32_bf16(av, bv, acc[t], 0, 0, 0);
        }
    }

#pragma unroll
    for (int t = 0; t < 4; ++t) {
        int c = 16 * t + l15;
        float b = bias_l[c];
#pragma unroll
        for (int i = 0; i < 4; ++i) {
            int n = n0 + 16 * wave + 4 * lg + i;
            if (n < N) {
                float v = acc[t][i] + b;
                xout[(size_t)n * DIM + c] = (__bf16)fmaxf(v, 0.f);
            }
        }
    }
}

// ---------------- score ----------------
__global__ __launch_bounds__(256) void score_kernel(const __bf16* __restrict__ xb,
                                                    const int* __restrict__ s,
                                                    const int* __restrict__ t,
                                                    float* __restrict__ out, int T) {
    int i = blockIdx.x * 4 + (threadIdx.x >> 6);
    if (i >= T) return;
    int lane = threadIdx.x & 63;
    float p = (float)xb[(size_t)s[i] * DIM + lane] * (float)xb[(size_t)t[i] * DIM + lane];
#pragma unroll
    for (int off = 32; off > 0; off >>= 1) p += __shfl_down(p, off, 64);
    if (lane == 0) out[i] = p;
}

extern "C" void kernel_launch(void* const* d_in, const int* in_sizes, int n_in,
                              void* d_out, int out_size, void* d_ws, size_t ws_size,
                              hipStream_t stream) {
    const int*   x_idx  = (const int*)d_in[0];
    const int*   eidx   = (const int*)d_in[1];   // [2,E]
    const int*   etyp   = (const int*)d_in[2];   // [E]
    const int*   tidx   = (const int*)d_in[3];   // [2,T]
    const float* emb    = (const float*)d_in[4]; // [N,64]
    const float* weight = (const float*)d_in[5]; // [L,8,64,64]
    const float* root   = (const float*)d_in[6]; // [L,64,64]
    const float* bias   = (const float*)d_in[7]; // [L,64]

    int N = in_sizes[0];
    int E = in_sizes[2];
    int T = in_sizes[3] / 2;
    int L = in_sizes[5] / (NREL * DIM * DIM);

    const int* src = eidx;
    const int* dst = eidx + E;
    const int* ts  = tidx;
    const int* tt  = tidx + T;
    float* out = (float*)d_out;

    int epad_cap = E + 3 * N * NREL + 64;   // worst-case padded edge count

    // ---- workspace carve-up ----
    char* p = (char*)d_ws;
    auto alloc = [&](size_t bytes) -> void* {
        void* r = (void*)p;
        p += (bytes + 255) & ~(size_t)255;
        return r;
    };
    __bf16* Sx      = (__bf16*)alloc((size_t)N * KS * sizeof(__bf16));
    __bf16* xb      = (__bf16*)alloc((size_t)(N + 1) * DIM * sizeof(__bf16));  // +1 zero row
    __bf16* Wt      = (__bf16*)alloc((size_t)L * 64 * KTOT * sizeof(__bf16));
    int*    srcs    = (int*)   alloc((size_t)epad_cap * sizeof(int));
    int*    deg8    = (int*)   alloc((size_t)N * 8 * 2 * sizeof(int));  // deg8 + cursor8
    int*    cursor8 = deg8 + (size_t)N * 8;
    int*    rp      = (int*)   alloc(((size_t)N * 8 + 1) * sizeof(int));
    int*    offs    = (int*)   alloc((size_t)N * sizeof(int));
    float*  invdeg  = (float*) alloc((size_t)N * sizeof(float));
    int*    bsum    = (int*)   alloc(1024 * sizeof(int));

    int nb = (N + 255) / 256;

    hipMemsetAsync(deg8, 0, (size_t)N * 8 * 2 * sizeof(int), stream);
    histgather_kernel<<<((size_t)N * DIM + 255) / 256, 256, 0, stream>>>(
        dst, etyp, deg8, x_idx, emb, xb, srcs, N, E, epad_cap);
    scan1_kernel<<<nb, 256, 0, stream>>>(deg8, offs, bsum, invdeg, N);
    {
        int wtotal = L * 64 * KTOT;
        int wblocks = 1 + (wtotal + 511) / 512;
        scan2wcat_kernel<<<wblocks, 512, 0, stream>>>(bsum, nb, weight, root, Wt, L);
    }
    rpbuild_kernel<<<nb, 256, 0, stream>>>(deg8, offs, bsum, rp, cursor8, N);
    bucket_kernel<<<(E + 255) / 256, 256, 0, stream>>>(src, dst, etyp, rp, cursor8, srcs, E);

    int ntiles = (N + 63) / 64;
    for (int l = 0; l < L; ++l) {
        aggregate_kernel<<<(N + 3) / 4, 256, 0, stream>>>(xb, srcs, rp, invdeg, Sx, N);
        gemm_kernel<<<ntiles, 256, 0, stream>>>(Sx, xb,
                                                Wt + (size_t)l * 64 * KTOT,
                                                bias + (size_t)l * DIM,
                                                xb, N);
    }

    score_kernel<<<(T + 3) / 4, 256, 0, stream>>>(xb, ts, tt, out, T);
}

// Round 9
// 479.444 us; speedup vs baseline: 2.5689x; 1.0415x over previous
//
#include <hip/hip_runtime.h>
#include <hip/hip_bf16.h>

#define DIM 64
#define NREL 8
#define KS 512              // Sx width (k-permuted: k = ch*8 + r)
#define KTOT 576            // GEMM K: 512 + 64 root

typedef __bf16 bf16x8 __attribute__((ext_vector_type(8)));
typedef __bf16 bf16x4 __attribute__((ext_vector_type(4)));
typedef float  f32x4  __attribute__((ext_vector_type(4)));

// ---------------- fused: hist + initial gather xb0 + srcs sentinel prefill + zero rows
__global__ __launch_bounds__(256) void histgather_kernel(const int* __restrict__ dst,
                                                         const int* __restrict__ et,
                                                         int* __restrict__ deg8,
                                                         const int* __restrict__ x_idx,
                                                         const float* __restrict__ emb,
                                                         __bf16* __restrict__ xb0,
                                                         __bf16* __restrict__ xb1,
                                                         int* __restrict__ srcs,
                                                         int N, int E, int epad_cap) {
    int i = blockIdx.x * 256 + threadIdx.x;
    if (i < N * DIM) {
        int n = i >> 6;
        int c = i & 63;
        xb0[i] = (__bf16)emb[(size_t)x_idx[n] * DIM + c];
    }
    if (i < DIM) {                                        // sentinel zero rows (index N)
        xb0[(size_t)N * DIM + i] = (__bf16)0.f;
        xb1[(size_t)N * DIM + i] = (__bf16)0.f;
    }
    if (i < epad_cap) srcs[i] = N;                        // padding -> sentinel
    if (i < E) atomicAdd(&deg8[dst[i] * 8 + et[i]], 1);
}

// ---------------- scan1 over per-dst PADDED totals + invdeg (true deg) ----------------
__global__ __launch_bounds__(256) void scan1_kernel(const int* __restrict__ deg8,
                                                    int* __restrict__ offs,
                                                    int* __restrict__ bsum,
                                                    float* __restrict__ invdeg, int N) {
    __shared__ int sd[256];
    int tid = threadIdx.x;
    int d = blockIdx.x * 256 + tid;
    int vpad = 0;
    if (d < N) {
        int vtrue = 0;
#pragma unroll
        for (int r = 0; r < NREL; ++r) {
            int dv = deg8[d * 8 + r];
            vtrue += dv;
            vpad += (dv + 3) & ~3;
        }
        invdeg[d] = 1.0f / fmaxf((float)vtrue, 1.0f);
    }
    sd[tid] = vpad;
    __syncthreads();
#pragma unroll
    for (int off = 1; off < 256; off <<= 1) {
        int t = (tid >= off) ? sd[tid - off] : 0;
        __syncthreads();
        sd[tid] += t;
        __syncthreads();
    }
    if (d < N) offs[d] = sd[tid] - vpad;
    if (tid == 255) bsum[blockIdx.x] = sd[255];
}

// ---------------- scan2 (block 0) + wcat (blocks >= 1) fused ----------------
// Wt[l][c][k]: k<512 -> k=ch*8+r maps weight[l][r][ch][c]; k>=512 -> root[l][k-512][c]
__global__ __launch_bounds__(512) void scan2wcat_kernel(int* __restrict__ bsum, int nb,
                                                        const float* __restrict__ weight,
                                                        const float* __restrict__ root,
                                                        __bf16* __restrict__ Wt, int L) {
    if (blockIdx.x == 0) {
        __shared__ int sd[512];
        int tid = threadIdx.x;
        int v = (tid < nb) ? bsum[tid] : 0;
        sd[tid] = v;
        __syncthreads();
#pragma unroll
        for (int off = 1; off < 512; off <<= 1) {
            int t = (tid >= off) ? sd[tid - off] : 0;
            __syncthreads();
            sd[tid] += t;
            __syncthreads();
        }
        if (tid < nb) bsum[tid] = sd[tid] - v;
    } else {
        int idx = (blockIdx.x - 1) * 512 + threadIdx.x;
        int total = L * 64 * KTOT;
        if (idx >= total) return;
        int l = idx / (64 * KTOT);
        int rem = idx - l * 64 * KTOT;
        int c = rem / KTOT;
        int k = rem - c * KTOT;
        float w;
        if (k < KS) {
            int ch = k >> 3, r = k & 7;
            w = weight[(((l * 8 + r) * 64) + ch) * 64 + c];
        } else {
            w = root[(l * 64 + (k - KS)) * 64 + c];
        }
        Wt[idx] = (__bf16)w;
    }
}

// ---------------- rp_pad build (padded per-cell starts) + cursor zero ----------------
__global__ __launch_bounds__(256) void rpbuild_kernel(const int* __restrict__ deg8,
                                                      const int* __restrict__ offs,
                                                      const int* __restrict__ bsum,
                                                      int* __restrict__ rp,
                                                      int* __restrict__ cursor8,
                                                      int N) {
    int d = blockIdx.x * 256 + threadIdx.x;
    if (d >= N) return;
    int base = offs[d] + bsum[blockIdx.x];
    int run = 0;
#pragma unroll
    for (int r = 0; r < NREL; ++r) {
        rp[d * 8 + r] = base + run;
        run += (deg8[d * 8 + r] + 3) & ~3;
        cursor8[d * 8 + r] = 0;
    }
    if (d == N - 1) rp[(size_t)N * 8] = base + run;   // E_pad total
}

// ---------------- bucket: srcs sorted by (dst, rel), padded cells ----------------
__global__ __launch_bounds__(256) void bucket_kernel(const int* __restrict__ src,
                                                     const int* __restrict__ dst,
                                                     const int* __restrict__ et,
                                                     const int* __restrict__ rp,
                                                     int* __restrict__ cursor8,
                                                     int* __restrict__ srcs, int E) {
    int i = blockIdx.x * 256 + threadIdx.x;
    if (i >= E) return;
    int cell = dst[i] * 8 + et[i];
    int p = rp[cell] + atomicAdd(&cursor8[cell], 1);
    srcs[p] = src[i];
}

// ---------------- aggregate v4: wave/dst; per-cell quads; scalar dwordx4 src loads
__global__ __launch_bounds__(256) void aggregate_kernel(const __bf16* __restrict__ xb,
                                                        const int* __restrict__ srcs,
                                                        const int* __restrict__ rp,
                                                        const float* __restrict__ invdeg,
                                                        __bf16* __restrict__ Sx, int N) {
    int d0 = blockIdx.x * 4 + (threadIdx.x >> 6);
    if (d0 >= N) return;
    int d = __builtin_amdgcn_readfirstlane(d0);
    int lane = threadIdx.x & 63;

    int rpv[9];
#pragma unroll
    for (int r = 0; r < 9; ++r) rpv[r] = rp[d * 8 + r];   // scalar loads (uniform)

    float facc[NREL];
#pragma unroll
    for (int r = 0; r < NREL; ++r) {                      // r compile-time -> named acc regs
        float acc = 0.f;
        for (int q = rpv[r]; q < rpv[r + 1]; q += 4) {    // uniform bounds, step 4
            int4 sv = *reinterpret_cast<const int4*>(srcs + q);   // s_load_dwordx4
            float v0 = (float)xb[(size_t)sv.x * DIM + lane];      // 4 independent gathers
            float v1 = (float)xb[(size_t)sv.y * DIM + lane];      // (sentinel N -> zero row)
            float v2 = (float)xb[(size_t)sv.z * DIM + lane];
            float v3 = (float)xb[(size_t)sv.w * DIM + lane];
            acc += (v0 + v1) + (v2 + v3);
        }
        facc[r] = acc;
    }

    float inv = invdeg[d];
    bf16x8 h;
#pragma unroll
    for (int r = 0; r < NREL; ++r) h[r] = (__bf16)(facc[r] * inv);
    // k-permuted row: element k = ch*8 + r, lane stores ch=lane -> 16B contiguous
    *reinterpret_cast<bf16x8*>(Sx + (size_t)d * KS + lane * 8) = h;
}

// ---------------- GEMM v2: W-in-registers (A-operand), Sx streamed (B-operand)
// wave w holds c-tile w: A-frags afrag[kk] = Wt[16w + l15][kk*32 + lg*8 ..+8], all K.
// Grid-stride over 16-row n-tiles; per tile: 18 independent B-loads + 18 MFMA.
// D: row = c-in-tile (4*lg+i), col = n (l15). Store xout[n][16w+4lg .. +4].
// NOTE: xout MUST NOT alias xin (waves share rows, split channels -> WAR race if in-place).
__global__ __launch_bounds__(256) void gemm_kernel(const __bf16* __restrict__ Sx,
                                                   const __bf16* __restrict__ xin,
                                                   const __bf16* __restrict__ Wt,    // [64][576]
                                                   const float* __restrict__ bias_l, // [64]
                                                   __bf16* __restrict__ xout, int N) {
    int wave = threadIdx.x >> 6;
    int lane = threadIdx.x & 63;
    int l15 = lane & 15;
    int lg  = lane >> 4;

    // hoist A (weights) into registers: 18 x 4 VGPRs = 72 VGPRs
    bf16x8 afrag[KTOT / 32];
    {
        const __bf16* wrow = Wt + (size_t)(16 * wave + l15) * KTOT + lg * 8;
#pragma unroll
        for (int kk = 0; kk < KTOT / 32; ++kk)
            afrag[kk] = *reinterpret_cast<const bf16x8*>(wrow + kk * 32);
    }
    int cbase = 16 * wave + 4 * lg;
    f32x4 bias4 = *reinterpret_cast<const f32x4*>(bias_l + cbase);

    int ntiles = (N + 15) >> 4;
    for (int tile = blockIdx.x; tile < ntiles; tile += gridDim.x) {
        int n = tile * 16 + l15;
        int nc = (n < N) ? n : (N - 1);                   // clamped load, guarded store
        const __bf16* srow = Sx  + (size_t)nc * KS  + lg * 8;
        const __bf16* xrow = xin + (size_t)nc * DIM + lg * 8;

        f32x4 acc = (f32x4){0.f, 0.f, 0.f, 0.f};
#pragma unroll
        for (int kk = 0; kk < KS / 32; ++kk) {
            bf16x8 bv = *reinterpret_cast<const bf16x8*>(srow + kk * 32);
            acc = __builtin_amdgcn_mfma_f32_16x16x32_bf16(afrag[kk], bv, acc, 0, 0, 0);
        }
#pragma unroll
        for (int kk = 0; kk < DIM / 32; ++kk) {
            bf16x8 bv = *reinterpret_cast<const bf16x8*>(xrow + kk * 32);
            acc = __builtin_amdgcn_mfma_f32_16x16x32_bf16(afrag[KS / 32 + kk], bv, acc, 0, 0, 0);
        }

        if (n < N) {
            bf16x4 h;
#pragma unroll
            for (int i = 0; i < 4; ++i)
                h[i] = (__bf16)fmaxf(acc[i] + bias4[i], 0.f);
            *reinterpret_cast<bf16x4*>(xout + (size_t)n * DIM + cbase) = h;
        }
    }
}

// ---------------- score ----------------
__global__ __launch_bounds__(256) void score_kernel(const __bf16* __restrict__ xb,
                                                    const int* __restrict__ s,
                                                    const int* __restrict__ t,
                                                    float* __restrict__ out, int T) {
    int i = blockIdx.x * 4 + (threadIdx.x >> 6);
    if (i >= T) return;
    int lane = threadIdx.x & 63;
    float p = (float)xb[(size_t)s[i] * DIM + lane] * (float)xb[(size_t)t[i] * DIM + lane];
#pragma unroll
    for (int off = 32; off > 0; off >>= 1) p += __shfl_down(p, off, 64);
    if (lane == 0) out[i] = p;
}

extern "C" void kernel_launch(void* const* d_in, const int* in_sizes, int n_in,
                              void* d_out, int out_size, void* d_ws, size_t ws_size,
                              hipStream_t stream) {
    const int*   x_idx  = (const int*)d_in[0];
    const int*   eidx   = (const int*)d_in[1];   // [2,E]
    const int*   etyp   = (const int*)d_in[2];   // [E]
    const int*   tidx   = (const int*)d_in[3];   // [2,T]
    const float* emb    = (const float*)d_in[4]; // [N,64]
    const float* weight = (const float*)d_in[5]; // [L,8,64,64]
    const float* root   = (const float*)d_in[6]; // [L,64,64]
    const float* bias   = (const float*)d_in[7]; // [L,64]

    int N = in_sizes[0];
    int E = in_sizes[2];
    int T = in_sizes[3] / 2;
    int L = in_sizes[5] / (NREL * DIM * DIM);

    const int* src = eidx;
    const int* dst = eidx + E;
    const int* ts  = tidx;
    const int* tt  = tidx + T;
    float* out = (float*)d_out;

    int epad_cap = E + 3 * N * NREL + 64;   // worst-case padded edge count

    // ---- workspace carve-up ----
    char* p = (char*)d_ws;
    auto alloc = [&](size_t bytes) -> void* {
        void* r = (void*)p;
        p += (bytes + 255) & ~(size_t)255;
        return r;
    };
    __bf16* Sx      = (__bf16*)alloc((size_t)N * KS * sizeof(__bf16));
    __bf16* xb0     = (__bf16*)alloc((size_t)(N + 1) * DIM * sizeof(__bf16));  // +1 zero row
    __bf16* xb1     = (__bf16*)alloc((size_t)(N + 1) * DIM * sizeof(__bf16));  // ping-pong
    __bf16* Wt      = (__bf16*)alloc((size_t)L * 64 * KTOT * sizeof(__bf16));
    int*    srcs    = (int*)   alloc((size_t)epad_cap * sizeof(int));
    int*    deg8    = (int*)   alloc((size_t)N * 8 * 2 * sizeof(int));  // deg8 + cursor8
    int*    cursor8 = deg8 + (size_t)N * 8;
    int*    rp      = (int*)   alloc(((size_t)N * 8 + 1) * sizeof(int));
    int*    offs    = (int*)   alloc((size_t)N * sizeof(int));
    float*  invdeg  = (float*) alloc((size_t)N * sizeof(float));
    int*    bsum    = (int*)   alloc(1024 * sizeof(int));

    int nb = (N + 255) / 256;

    hipMemsetAsync(deg8, 0, (size_t)N * 8 * 2 * sizeof(int), stream);
    histgather_kernel<<<((size_t)N * DIM + 255) / 256, 256, 0, stream>>>(
        dst, etyp, deg8, x_idx, emb, xb0, xb1, srcs, N, E, epad_cap);
    scan1_kernel<<<nb, 256, 0, stream>>>(deg8, offs, bsum, invdeg, N);
    {
        int wtotal = L * 64 * KTOT;
        int wblocks = 1 + (wtotal + 511) / 512;
        scan2wcat_kernel<<<wblocks, 512, 0, stream>>>(bsum, nb, weight, root, Wt, L);
    }
    rpbuild_kernel<<<nb, 256, 0, stream>>>(deg8, offs, bsum, rp, cursor8, N);
    bucket_kernel<<<(E + 255) / 256, 256, 0, stream>>>(src, dst, etyp, rp, cursor8, srcs, E);

    __bf16* xcur = xb0;
    __bf16* xnxt = xb1;
    for (int l = 0; l < L; ++l) {
        aggregate_kernel<<<(N + 3) / 4, 256, 0, stream>>>(xcur, srcs, rp, invdeg, Sx, N);
        gemm_kernel<<<1024, 256, 0, stream>>>(Sx, xcur,
                                              Wt + (size_t)l * 64 * KTOT,
                                              bias + (size_t)l * DIM,
                                              xnxt, N);
        __bf16* tmp = xcur; xcur = xnxt; xnxt = tmp;
    }

    score_kernel<<<(T + 3) / 4, 256, 0, stream>>>(xcur, ts, tt, out, T);
}

// Round 10
// 445.232 us; speedup vs baseline: 2.7662x; 1.0768x over previous
//
#include <hip/hip_runtime.h>
#include <hip/hip_bf16.h>

#define DIM 64
#define NREL 8
#define KS 512              // Sx width (k-permuted: k = ch*8 + r)
#define KTOT 576            // GEMM K: 512 + 64 root

typedef __bf16 bf16x8 __attribute__((ext_vector_type(8)));
typedef __bf16 bf16x4 __attribute__((ext_vector_type(4)));
typedef float  f32x4  __attribute__((ext_vector_type(4)));

// ---------------- fused: hist (rank-returning) + initial gather + sentinels ----------------
__global__ __launch_bounds__(256) void histgather_kernel(const int* __restrict__ dst,
                                                         const int* __restrict__ et,
                                                         int* __restrict__ deg8,
                                                         int* __restrict__ eoff,
                                                         const int* __restrict__ x_idx,
                                                         const float* __restrict__ emb,
                                                         __bf16* __restrict__ xb0,
                                                         __bf16* __restrict__ xb1,
                                                         int* __restrict__ srcs,
                                                         int N, int E, int epad_cap) {
    int i = blockIdx.x * 256 + threadIdx.x;
    if (i < N * DIM) {
        int n = i >> 6;
        int c = i & 63;
        xb0[i] = (__bf16)emb[(size_t)x_idx[n] * DIM + c];
    }
    if (i < DIM) {                                        // sentinel zero rows (index N)
        xb0[(size_t)N * DIM + i] = (__bf16)0.f;
        xb1[(size_t)N * DIM + i] = (__bf16)0.f;
    }
    if (i < epad_cap) srcs[i] = N;                        // padding -> sentinel
    if (i < E) eoff[i] = atomicAdd(&deg8[dst[i] * 8 + et[i]], 1);  // rank within cell
}

// ---------------- scan1 over per-dst PADDED totals + invdeg (true deg) ----------------
__global__ __launch_bounds__(256) void scan1_kernel(const int* __restrict__ deg8,
                                                    int* __restrict__ offs,
                                                    int* __restrict__ bsum,
                                                    float* __restrict__ invdeg, int N) {
    __shared__ int sd[256];
    int tid = threadIdx.x;
    int d = blockIdx.x * 256 + tid;
    int vpad = 0;
    if (d < N) {
        int vtrue = 0;
#pragma unroll
        for (int r = 0; r < NREL; ++r) {
            int dv = deg8[d * 8 + r];
            vtrue += dv;
            vpad += (dv + 3) & ~3;
        }
        invdeg[d] = 1.0f / fmaxf((float)vtrue, 1.0f);
    }
    sd[tid] = vpad;
    __syncthreads();
#pragma unroll
    for (int off = 1; off < 256; off <<= 1) {
        int t = (tid >= off) ? sd[tid - off] : 0;
        __syncthreads();
        sd[tid] += t;
        __syncthreads();
    }
    if (d < N) offs[d] = sd[tid] - vpad;
    if (tid == 255) bsum[blockIdx.x] = sd[255];
}

// ---------------- scan2 (block 0) + wcat (blocks >= 1) fused ----------------
// Wt[l][c][k]: k<512 -> k=ch*8+r maps weight[l][r][ch][c]; k>=512 -> root[l][k-512][c]
__global__ __launch_bounds__(512) void scan2wcat_kernel(int* __restrict__ bsum, int nb,
                                                        const float* __restrict__ weight,
                                                        const float* __restrict__ root,
                                                        __bf16* __restrict__ Wt, int L) {
    if (blockIdx.x == 0) {
        __shared__ int sd[512];
        int tid = threadIdx.x;
        int v = (tid < nb) ? bsum[tid] : 0;
        sd[tid] = v;
        __syncthreads();
#pragma unroll
        for (int off = 1; off < 512; off <<= 1) {
            int t = (tid >= off) ? sd[tid - off] : 0;
            __syncthreads();
            sd[tid] += t;
            __syncthreads();
        }
        if (tid < nb) bsum[tid] = sd[tid] - v;
    } else {
        int idx = (blockIdx.x - 1) * 512 + threadIdx.x;
        int total = L * 64 * KTOT;
        if (idx >= total) return;
        int l = idx / (64 * KTOT);
        int rem = idx - l * 64 * KTOT;
        int c = rem / KTOT;
        int k = rem - c * KTOT;
        float w;
        if (k < KS) {
            int ch = k >> 3, r = k & 7;
            w = weight[(((l * 8 + r) * 64) + ch) * 64 + c];
        } else {
            w = root[(l * 64 + (k - KS)) * 64 + c];
        }
        Wt[idx] = (__bf16)w;
    }
}

// ---------------- rp_pad build (padded per-cell starts) ----------------
__global__ __launch_bounds__(256) void rpbuild_kernel(const int* __restrict__ deg8,
                                                      const int* __restrict__ offs,
                                                      const int* __restrict__ bsum,
                                                      int* __restrict__ rp,
                                                      int N) {
    int d = blockIdx.x * 256 + threadIdx.x;
    if (d >= N) return;
    int base = offs[d] + bsum[blockIdx.x];
    int run = 0;
#pragma unroll
    for (int r = 0; r < NREL; ++r) {
        rp[d * 8 + r] = base + run;
        run += (deg8[d * 8 + r] + 3) & ~3;
    }
    if (d == N - 1) rp[(size_t)N * 8] = base + run;   // E_pad total
}

// ---------------- bucket: atomic-free scatter, 2 coalesced half-streams per thread
__global__ __launch_bounds__(256) void bucket_kernel(const int* __restrict__ src,
                                                     const int* __restrict__ dst,
                                                     const int* __restrict__ et,
                                                     const int* __restrict__ rp,
                                                     const int* __restrict__ eoff,
                                                     int* __restrict__ srcs, int E) {
    int i = blockIdx.x * 256 + threadIdx.x;
    int half = (E + 1) >> 1;
    if (i >= half) return;
    int iB = i + half;
    bool hasB = iB < E;
    // issue both edges' loads before either store (independent chains -> 2x MLP)
    int cellA = dst[i] * 8 + et[i];
    int cellB = hasB ? dst[iB] * 8 + et[iB] : 0;
    int rA = rp[cellA];
    int rB = hasB ? rp[cellB] : 0;
    int oA = eoff[i];
    int oB = hasB ? eoff[iB] : 0;
    int sA = src[i];
    int sB = hasB ? src[iB] : 0;
    srcs[rA + oA] = sA;
    if (hasB) srcs[rB + oB] = sB;
}

// ---------------- aggregate v4: wave/dst; per-cell quads; scalar dwordx4 src loads
__global__ __launch_bounds__(256) void aggregate_kernel(const __bf16* __restrict__ xb,
                                                        const int* __restrict__ srcs,
                                                        const int* __restrict__ rp,
                                                        const float* __restrict__ invdeg,
                                                        __bf16* __restrict__ Sx, int N) {
    int d0 = blockIdx.x * 4 + (threadIdx.x >> 6);
    if (d0 >= N) return;
    int d = __builtin_amdgcn_readfirstlane(d0);
    int lane = threadIdx.x & 63;

    int rpv[9];
#pragma unroll
    for (int r = 0; r < 9; ++r) rpv[r] = rp[d * 8 + r];   // scalar loads (uniform)

    float facc[NREL];
#pragma unroll
    for (int r = 0; r < NREL; ++r) {                      // r compile-time -> named acc regs
        float acc = 0.f;
        for (int q = rpv[r]; q < rpv[r + 1]; q += 4) {    // uniform bounds, step 4
            int4 sv = *reinterpret_cast<const int4*>(srcs + q);   // s_load_dwordx4
            float v0 = (float)xb[(size_t)sv.x * DIM + lane];      // 4 independent gathers
            float v1 = (float)xb[(size_t)sv.y * DIM + lane];      // (sentinel N -> zero row)
            float v2 = (float)xb[(size_t)sv.z * DIM + lane];
            float v3 = (float)xb[(size_t)sv.w * DIM + lane];
            acc += (v0 + v1) + (v2 + v3);
        }
        facc[r] = acc;
    }

    float inv = invdeg[d];
    bf16x8 h;
#pragma unroll
    for (int r = 0; r < NREL; ++r) h[r] = (__bf16)(facc[r] * inv);
    // k-permuted row: element k = ch*8 + r, lane stores ch=lane -> 16B contiguous
    *reinterpret_cast<bf16x8*>(Sx + (size_t)d * KS + lane * 8) = h;
}

// ---------------- GEMM v2: W-in-registers (A-operand), Sx streamed (B-operand)
// NOTE: xout MUST NOT alias xin (waves share rows, split channels -> WAR race if in-place).
__global__ __launch_bounds__(256) void gemm_kernel(const __bf16* __restrict__ Sx,
                                                   const __bf16* __restrict__ xin,
                                                   const __bf16* __restrict__ Wt,    // [64][576]
                                                   const float* __restrict__ bias_l, // [64]
                                                   __bf16* __restrict__ xout, int N) {
    int wave = threadIdx.x >> 6;
    int lane = threadIdx.x & 63;
    int l15 = lane & 15;
    int lg  = lane >> 4;

    // hoist A (weights) into registers: 18 x 4 VGPRs = 72 VGPRs
    bf16x8 afrag[KTOT / 32];
    {
        const __bf16* wrow = Wt + (size_t)(16 * wave + l15) * KTOT + lg * 8;
#pragma unroll
        for (int kk = 0; kk < KTOT / 32; ++kk)
            afrag[kk] = *reinterpret_cast<const bf16x8*>(wrow + kk * 32);
    }
    int cbase = 16 * wave + 4 * lg;
    f32x4 bias4 = *reinterpret_cast<const f32x4*>(bias_l + cbase);

    int ntiles = (N + 15) >> 4;
    for (int tile = blockIdx.x; tile < ntiles; tile += gridDim.x) {
        int n = tile * 16 + l15;
        int nc = (n < N) ? n : (N - 1);                   // clamped load, guarded store
        const __bf16* srow = Sx  + (size_t)nc * KS  + lg * 8;
        const __bf16* xrow = xin + (size_t)nc * DIM + lg * 8;

        f32x4 acc = (f32x4){0.f, 0.f, 0.f, 0.f};
#pragma unroll
        for (int kk = 0; kk < KS / 32; ++kk) {
            bf16x8 bv = *reinterpret_cast<const bf16x8*>(srow + kk * 32);
            acc = __builtin_amdgcn_mfma_f32_16x16x32_bf16(afrag[kk], bv, acc, 0, 0, 0);
        }
#pragma unroll
        for (int kk = 0; kk < DIM / 32; ++kk) {
            bf16x8 bv = *reinterpret_cast<const bf16x8*>(xrow + kk * 32);
            acc = __builtin_amdgcn_mfma_f32_16x16x32_bf16(afrag[KS / 32 + kk], bv, acc, 0, 0, 0);
        }

        if (n < N) {
            bf16x4 h;
#pragma unroll
            for (int i = 0; i < 4; ++i)
                h[i] = (__bf16)fmaxf(acc[i] + bias4[i], 0.f);
            *reinterpret_cast<bf16x4*>(xout + (size_t)n * DIM + cbase) = h;
        }
    }
}

// ---------------- score ----------------
__global__ __launch_bounds__(256) void score_kernel(const __bf16* __restrict__ xb,
                                                    const int* __restrict__ s,
                                                    const int* __restrict__ t,
                                                    float* __restrict__ out, int T) {
    int i = blockIdx.x * 4 + (threadIdx.x >> 6);
    if (i >= T) return;
    int lane = threadIdx.x & 63;
    float p = (float)xb[(size_t)s[i] * DIM + lane] * (float)xb[(size_t)t[i] * DIM + lane];
#pragma unroll
    for (int off = 32; off > 0; off >>= 1) p += __shfl_down(p, off, 64);
    if (lane == 0) out[i] = p;
}

extern "C" void kernel_launch(void* const* d_in, const int* in_sizes, int n_in,
                              void* d_out, int out_size, void* d_ws, size_t ws_size,
                              hipStream_t stream) {
    const int*   x_idx  = (const int*)d_in[0];
    const int*   eidx   = (const int*)d_in[1];   // [2,E]
    const int*   etyp   = (const int*)d_in[2];   // [E]
    const int*   tidx   = (const int*)d_in[3];   // [2,T]
    const float* emb    = (const float*)d_in[4]; // [N,64]
    const float* weight = (const float*)d_in[5]; // [L,8,64,64]
    const float* root   = (const float*)d_in[6]; // [L,64,64]
    const float* bias   = (const float*)d_in[7]; // [L,64]

    int N = in_sizes[0];
    int E = in_sizes[2];
    int T = in_sizes[3] / 2;
    int L = in_sizes[5] / (NREL * DIM * DIM);

    const int* src = eidx;
    const int* dst = eidx + E;
    const int* ts  = tidx;
    const int* tt  = tidx + T;
    float* out = (float*)d_out;

    int epad_cap = E + 3 * N * NREL + 64;   // worst-case padded edge count

    // ---- workspace carve-up ----
    char* p = (char*)d_ws;
    auto alloc = [&](size_t bytes) -> void* {
        void* r = (void*)p;
        p += (bytes + 255) & ~(size_t)255;
        return r;
    };
    __bf16* Sx      = (__bf16*)alloc((size_t)N * KS * sizeof(__bf16));
    __bf16* xb0     = (__bf16*)alloc((size_t)(N + 1) * DIM * sizeof(__bf16));  // +1 zero row
    __bf16* xb1     = (__bf16*)alloc((size_t)(N + 1) * DIM * sizeof(__bf16));  // ping-pong
    __bf16* Wt      = (__bf16*)alloc((size_t)L * 64 * KTOT * sizeof(__bf16));
    int*    srcs    = (int*)   alloc((size_t)epad_cap * sizeof(int));
    int*    eoff    = (int*)   alloc((size_t)E * sizeof(int));
    int*    deg8    = (int*)   alloc((size_t)N * 8 * sizeof(int));
    int*    rp      = (int*)   alloc(((size_t)N * 8 + 1) * sizeof(int));
    int*    offs    = (int*)   alloc((size_t)N * sizeof(int));
    float*  invdeg  = (float*) alloc((size_t)N * sizeof(float));
    int*    bsum    = (int*)   alloc(1024 * sizeof(int));

    int nb = (N + 255) / 256;

    hipMemsetAsync(deg8, 0, (size_t)N * 8 * sizeof(int), stream);
    histgather_kernel<<<((size_t)N * DIM + 255) / 256, 256, 0, stream>>>(
        dst, etyp, deg8, eoff, x_idx, emb, xb0, xb1, srcs, N, E, epad_cap);
    scan1_kernel<<<nb, 256, 0, stream>>>(deg8, offs, bsum, invdeg, N);
    {
        int wtotal = L * 64 * KTOT;
        int wblocks = 1 + (wtotal + 511) / 512;
        scan2wcat_kernel<<<wblocks, 512, 0, stream>>>(bsum, nb, weight, root, Wt, L);
    }
    rpbuild_kernel<<<nb, 256, 0, stream>>>(deg8, offs, bsum, rp, N);
    {
        int half = (E + 1) / 2;
        bucket_kernel<<<(half + 255) / 256, 256, 0, stream>>>(src, dst, etyp, rp, eoff, srcs, E);
    }

    __bf16* xcur = xb0;
    __bf16* xnxt = xb1;
    for (int l = 0; l < L; ++l) {
        aggregate_kernel<<<(N + 3) / 4, 256, 0, stream>>>(xcur, srcs, rp, invdeg, Sx, N);
        gemm_kernel<<<1024, 256, 0, stream>>>(Sx, xcur,
                                              Wt + (size_t)l * 64 * KTOT,
                                              bias + (size_t)l * DIM,
                                              xnxt, N);
        __bf16* tmp = xcur; xcur = xnxt; xnxt = tmp;
    }

    score_kernel<<<(T + 3) / 4, 256, 0, stream>>>(xcur, ts, tt, out, T);
}